// Round 1
// baseline (137.286 us; speedup 1.0000x reference)
//
#include <hip/hip_runtime.h>
#include <math.h>

// VectorExpansionCalculator: per-edge radial basis (8 sines w/ cosine cutoff)
// outer-product with real spherical harmonics l=0..3 (n_max = 8,7,6,5).
// Output f32, blocks concatenated flat: [E,1,8] | [E,3,7] | [E,5,6] | [E,7,5].
// Memory-bound: ~376 MB written per call.

#define RCUT 5.0f
#define EPSF 1e-12f

__global__ __launch_bounds__(256) void vexp_kernel(
    const float* __restrict__ v, float* __restrict__ out, int E) {
  int e = blockIdx.x * blockDim.x + threadIdx.x;
  if (e >= E) return;

  float x = v[3 * e + 0];
  float y = v[3 * e + 1];
  float z = v[3 * e + 2];

  float r2 = x * x + y * y + z * z;
  float r = sqrtf(r2);
  float ir = 1.0f / (r + EPSF);

  // ---- radial basis: rb[n] = fcut * sin((n+1)*pi*r/RCUT) / (r+eps) ----
  float theta = (3.14159265358979323846f / RCUT) * r;
  float s, c;
  sincosf(theta, &s, &c);
  float fcut = (r < RCUT) ? 0.5f * (c + 1.0f) : 0.0f;
  float g = fcut * ir;

  float rb[8];
  {
    float twoc = 2.0f * c;
    float sp = 0.0f;   // sin(0*theta)
    float sn = s;      // sin(1*theta)
    rb[0] = sn * g;
#pragma unroll
    for (int n = 1; n < 8; ++n) {
      float s2 = twoc * sn - sp;
      sp = sn;
      sn = s2;
      rb[n] = sn * g;
    }
  }

  // ---- unit direction + spherical harmonics ----
  float ux = x * ir, uy = y * ir, uz = z * ir;
  float xx = ux * ux, yy = uy * uy, zz = uz * uz;

  const float c1 = 0.48860251190291992f;   // sqrt(3/(4pi))
  float sh1_0 = c1 * uy;
  float sh1_1 = c1 * uz;
  float sh1_2 = c1 * ux;

  const float c2a = 1.09254843059207907f;  // 0.5*sqrt(15/pi)
  const float c2b = 0.31539156525252001f;  // 0.25*sqrt(5/pi)
  const float c2c = 0.54627421529603953f;  // 0.25*sqrt(15/pi)
  float sh2_0 = c2a * ux * uy;
  float sh2_1 = c2a * uy * uz;
  float sh2_2 = c2b * (2.0f * zz - xx - yy);
  float sh2_3 = c2a * ux * uz;
  float sh2_4 = c2c * (xx - yy);

  const float c3a = 0.59004358992664352f;  // 0.25*sqrt(35/(2pi))
  const float c3b = 2.89061144264055405f;  // 0.5*sqrt(105/pi)
  const float c3c = 0.45704579946446574f;  // 0.25*sqrt(21/(2pi))
  const float c3d = 0.37317633259011546f;  // 0.25*sqrt(7/pi)
  const float c3e = 1.44530572132027702f;  // 0.25*sqrt(105/pi)
  float sh3_0 = c3a * uy * (3.0f * xx - yy);
  float sh3_1 = c3b * ux * uy * uz;
  float sh3_2 = c3c * uy * (4.0f * zz - xx - yy);
  float sh3_3 = c3d * uz * (2.0f * zz - 3.0f * xx - 3.0f * yy);
  float sh3_4 = c3c * ux * (4.0f * zz - xx - yy);
  float sh3_5 = c3e * uz * (xx - yy);
  float sh3_6 = c3a * ux * (xx - 3.0f * yy);

  size_t E_ = (size_t)E;

  // ---- block 0: [E,1,8] @ 0, 32B/edge, 16B aligned -> 2x float4 ----
  const float y0c = 0.28209479177387814f;  // 0.5*sqrt(1/pi)
  {
    float4* o0 = reinterpret_cast<float4*>(out + (size_t)e * 8);
    o0[0] = make_float4(y0c * rb[0], y0c * rb[1], y0c * rb[2], y0c * rb[3]);
    o0[1] = make_float4(y0c * rb[4], y0c * rb[5], y0c * rb[6], y0c * rb[7]);
  }

  // ---- block 1: [E,3,7] @ 8E ----
  {
    float* o1 = out + 8 * E_ + (size_t)e * 21;
    float sh1[3] = {sh1_0, sh1_1, sh1_2};
#pragma unroll
    for (int m = 0; m < 3; ++m)
#pragma unroll
      for (int n = 0; n < 7; ++n) o1[m * 7 + n] = sh1[m] * rb[n];
  }

  // ---- block 2: [E,5,6] @ 29E ----
  {
    float* o2 = out + 29 * E_ + (size_t)e * 30;
    float sh2[5] = {sh2_0, sh2_1, sh2_2, sh2_3, sh2_4};
#pragma unroll
    for (int m = 0; m < 5; ++m)
#pragma unroll
      for (int n = 0; n < 6; ++n) o2[m * 6 + n] = sh2[m] * rb[n];
  }

  // ---- block 3: [E,7,5] @ 59E ----
  {
    float* o3 = out + 59 * E_ + (size_t)e * 35;
    float sh3[7] = {sh3_0, sh3_1, sh3_2, sh3_3, sh3_4, sh3_5, sh3_6};
#pragma unroll
    for (int m = 0; m < 7; ++m)
#pragma unroll
      for (int n = 0; n < 5; ++n) o3[m * 5 + n] = sh3[m] * rb[n];
  }
}

extern "C" void kernel_launch(void* const* d_in, const int* in_sizes, int n_in,
                              void* d_out, int out_size, void* d_ws, size_t ws_size,
                              hipStream_t stream) {
  const float* v = (const float*)d_in[0];
  float* out = (float*)d_out;
  int E = in_sizes[0] / 3;
  int block = 256;
  int grid = (E + block - 1) / block;
  vexp_kernel<<<grid, block, 0, stream>>>(v, out, E);
}

// Round 2
// 79.426 us; speedup vs baseline: 1.7285x; 1.7285x over previous
//
#include <hip/hip_runtime.h>
#include <math.h>

// VectorExpansionCalculator: per-edge radial basis (8 sines w/ cosine cutoff)
// outer-product with real spherical harmonics l=0..3 (n_max = 8,7,6,5).
// Output f32 blocks concat flat: [E,1,8] | [E,3,7] | [E,5,6] | [E,7,5].
// Round 1 was store-request bound (scattered per-lane dword stores, ~64 L2
// requests per wave-store). Fix: per-wave LDS staging -> contiguous dwordx4.

#define RCUT 5.0f
#define EPSF 1e-12f

// Stage S floats/lane into wave-private LDS (linear [64][S]), then flush the
// wave's contiguous 64*S-float region with coalesced float4 stores.
template <int S>
__device__ __forceinline__ void stage_flush(float* __restrict__ lw,
                                            const float* __restrict__ vals,
                                            int lane,
                                            float4* __restrict__ g4) {
#pragma unroll
  for (int i = 0; i < S; ++i) lw[lane * S + i] = vals[i];
  // LDS is in-order per wave; compiler inserts lgkmcnt before dependent reads.
  const float4* l4 = reinterpret_cast<const float4*>(lw);
  constexpr int NF4 = 16 * S;                 // 64*S/4 float4s
  constexpr int NITER = (NF4 + 63) / 64;
#pragma unroll
  for (int it = 0; it < NITER; ++it) {
    int k = lane + it * 64;
    if ((NF4 % 64 == 0) || k < NF4) g4[k] = l4[k];
  }
}

__global__ __launch_bounds__(256) void vexp_kernel(const float* __restrict__ v,
                                                   float* __restrict__ out, int E) {
  __shared__ float4 lbuf[4][560];  // per-wave staging: 35*64 floats = 8960 B
  const int lane = threadIdx.x & 63;
  const int wave = threadIdx.x >> 6;
  const long long e0 = ((long long)blockIdx.x * 4 + wave) * 64;
  if (e0 >= E) return;
  const bool fullwave = (e0 + 64 <= (long long)E) && ((E & 3) == 0);
  const int e = (int)e0 + lane;
  const bool valid = e < E;

  float x = 0.0f, y = 0.0f, z = 0.0f;
  if (valid) {
    x = v[3 * (size_t)e + 0];
    y = v[3 * (size_t)e + 1];
    z = v[3 * (size_t)e + 2];
  }

  float r2 = x * x + y * y + z * z;
  float r = sqrtf(r2);
  float ir = 1.0f / (r + EPSF);

  // ---- radial basis: rb[n] = fcut * sin((n+1)*pi*r/RCUT) / (r+eps) ----
  float theta = (3.14159265358979323846f / RCUT) * r;
  float s, c;
  sincosf(theta, &s, &c);
  float fcut = (r < RCUT) ? 0.5f * (c + 1.0f) : 0.0f;
  float g = fcut * ir;

  float rb[8];
  {
    float twoc = 2.0f * c;
    float sp = 0.0f, sn = s;
    rb[0] = sn * g;
#pragma unroll
    for (int n = 1; n < 8; ++n) {
      float s2 = twoc * sn - sp;
      sp = sn;
      sn = s2;
      rb[n] = sn * g;
    }
  }

  // ---- unit direction + spherical harmonics ----
  float ux = x * ir, uy = y * ir, uz = z * ir;
  float xx = ux * ux, yy = uy * uy, zz = uz * uz;

  const float c1 = 0.48860251190291992f;
  float sh1[3] = {c1 * uy, c1 * uz, c1 * ux};

  const float c2a = 1.09254843059207907f;
  const float c2b = 0.31539156525252001f;
  const float c2c = 0.54627421529603953f;
  float sh2[5] = {c2a * ux * uy, c2a * uy * uz, c2b * (2.0f * zz - xx - yy),
                  c2a * ux * uz, c2c * (xx - yy)};

  const float c3a = 0.59004358992664352f;
  const float c3b = 2.89061144264055405f;
  const float c3c = 0.45704579946446574f;
  const float c3d = 0.37317633259011546f;
  const float c3e = 1.44530572132027702f;
  float sh3[7] = {c3a * uy * (3.0f * xx - yy),
                  c3b * ux * uy * uz,
                  c3c * uy * (4.0f * zz - xx - yy),
                  c3d * uz * (2.0f * zz - 3.0f * xx - 3.0f * yy),
                  c3c * ux * (4.0f * zz - xx - yy),
                  c3e * uz * (xx - yy),
                  c3a * ux * (xx - 3.0f * yy)};

  const size_t E_ = (size_t)E;
  float* lw = reinterpret_cast<float*>(lbuf[wave]);

  // ---- block 0: [E,1,8] @ 0 — per-thread 32B contiguous, direct float4 ----
  const float y0c = 0.28209479177387814f;
  if (valid) {
    float4* o0 = reinterpret_cast<float4*>(out + (size_t)e * 8);
    o0[0] = make_float4(y0c * rb[0], y0c * rb[1], y0c * rb[2], y0c * rb[3]);
    o0[1] = make_float4(y0c * rb[4], y0c * rb[5], y0c * rb[6], y0c * rb[7]);
  }

  float vals[35];

  // ---- block 1: [E,3,7] @ 8E ----
#pragma unroll
  for (int m = 0; m < 3; ++m)
#pragma unroll
    for (int n = 0; n < 7; ++n) vals[m * 7 + n] = sh1[m] * rb[n];
  if (fullwave) {
    stage_flush<21>(lw, vals, lane,
                    reinterpret_cast<float4*>(out + 8 * E_ + (size_t)e0 * 21));
  } else if (valid) {
    float* o = out + 8 * E_ + (size_t)e * 21;
#pragma unroll
    for (int i = 0; i < 21; ++i) o[i] = vals[i];
  }

  // ---- block 2: [E,5,6] @ 29E ----
#pragma unroll
  for (int m = 0; m < 5; ++m)
#pragma unroll
    for (int n = 0; n < 6; ++n) vals[m * 6 + n] = sh2[m] * rb[n];
  if (fullwave) {
    stage_flush<30>(lw, vals, lane,
                    reinterpret_cast<float4*>(out + 29 * E_ + (size_t)e0 * 30));
  } else if (valid) {
    float* o = out + 29 * E_ + (size_t)e * 30;
#pragma unroll
    for (int i = 0; i < 30; ++i) o[i] = vals[i];
  }

  // ---- block 3: [E,7,5] @ 59E ----
#pragma unroll
  for (int m = 0; m < 7; ++m)
#pragma unroll
    for (int n = 0; n < 5; ++n) vals[m * 5 + n] = sh3[m] * rb[n];
  if (fullwave) {
    stage_flush<35>(lw, vals, lane,
                    reinterpret_cast<float4*>(out + 59 * E_ + (size_t)e0 * 35));
  } else if (valid) {
    float* o = out + 59 * E_ + (size_t)e * 35;
#pragma unroll
    for (int i = 0; i < 35; ++i) o[i] = vals[i];
  }
}

extern "C" void kernel_launch(void* const* d_in, const int* in_sizes, int n_in,
                              void* d_out, int out_size, void* d_ws, size_t ws_size,
                              hipStream_t stream) {
  const float* v = (const float*)d_in[0];
  float* out = (float*)d_out;
  int E = in_sizes[0] / 3;
  int waves = (E + 63) / 64;
  int grid = (waves + 3) / 4;  // 4 waves (256 threads) per block
  vexp_kernel<<<grid, 256, 0, stream>>>(v, out, E);
}

// Round 4
// 74.864 us; speedup vs baseline: 1.8338x; 1.0609x over previous
//
#include <hip/hip_runtime.h>
#include <math.h>

// VectorExpansionCalculator: per-edge radial basis (8 sines w/ cosine cutoff)
// outer-product with real spherical harmonics l=0..3 (n_max = 8,7,6,5).
// Output f32 blocks concat flat: [E,1,8] | [E,3,7] | [E,5,6] | [E,7,5].
// R1: scattered scalar stores -> 137us (store-request bound).
// R2: per-wave LDS staging -> coalesced dwordx4 -> 79us (4.9 TB/s).
// R3: stage block0 too, native v_sin/v_cos, nontemporal stores.
//     (fix: use clang ext_vector_type for __builtin_nontemporal_store —
//      HIP's float4 struct is rejected by the builtin.)

#define RCUT 5.0f
#define EPSF 1e-12f

typedef float fx4 __attribute__((ext_vector_type(4)));

// Stage S floats/lane into wave-private LDS (linear [64][S]), then flush the
// wave's contiguous 64*S-float region with coalesced nontemporal 16B stores.
template <int S>
__device__ __forceinline__ void stage_flush(float* __restrict__ lw,
                                            const float* __restrict__ vals,
                                            int lane,
                                            fx4* __restrict__ g4) {
#pragma unroll
  for (int i = 0; i < S; ++i) lw[lane * S + i] = vals[i];
  // LDS is in-order per wave; compiler inserts lgkmcnt before dependent reads.
  const fx4* l4 = reinterpret_cast<const fx4*>(lw);
  constexpr int NF4 = 16 * S;                 // 64*S/4 16B-vectors
  constexpr int NITER = (NF4 + 63) / 64;
#pragma unroll
  for (int it = 0; it < NITER; ++it) {
    int k = lane + it * 64;
    if ((NF4 % 64 == 0) || k < NF4) __builtin_nontemporal_store(l4[k], &g4[k]);
  }
}

__global__ __launch_bounds__(256) void vexp_kernel(const float* __restrict__ v,
                                                   float* __restrict__ out, int E) {
  __shared__ fx4 lbuf[4][560];  // per-wave staging: 35*64 floats = 8960 B
  const int lane = threadIdx.x & 63;
  const int wave = threadIdx.x >> 6;
  const long long e0 = ((long long)blockIdx.x * 4 + wave) * 64;
  if (e0 >= E) return;
  const bool fullwave = (e0 + 64 <= (long long)E);
  const int e = (int)e0 + lane;
  const bool valid = e < E;

  float x = 0.0f, y = 0.0f, z = 0.0f;
  if (valid) {
    x = v[3 * (size_t)e + 0];
    y = v[3 * (size_t)e + 1];
    z = v[3 * (size_t)e + 2];
  }

  float r2 = x * x + y * y + z * z;
  float r = sqrtf(r2);
  float ir = 1.0f / (r + EPSF);

  // ---- radial basis: rb[n] = fcut * sin((n+1)*pi*r/RCUT) / (r+eps) ----
  // One native sin+cos; sin(n*theta) via Chebyshev recurrence.
  float theta = (3.14159265358979323846f / RCUT) * r;
  float s = __sinf(theta);
  float c = __cosf(theta);
  float fcut = (r < RCUT) ? 0.5f * (c + 1.0f) : 0.0f;
  float g = fcut * ir;

  float rb[8];
  {
    float twoc = 2.0f * c;
    float sp = 0.0f, sn = s;
    rb[0] = sn * g;
#pragma unroll
    for (int n = 1; n < 8; ++n) {
      float s2 = twoc * sn - sp;
      sp = sn;
      sn = s2;
      rb[n] = sn * g;
    }
  }

  // ---- unit direction + spherical harmonics ----
  float ux = x * ir, uy = y * ir, uz = z * ir;
  float xx = ux * ux, yy = uy * uy, zz = uz * uz;

  const float c1 = 0.48860251190291992f;
  float sh1[3] = {c1 * uy, c1 * uz, c1 * ux};

  const float c2a = 1.09254843059207907f;
  const float c2b = 0.31539156525252001f;
  const float c2c = 0.54627421529603953f;
  float sh2[5] = {c2a * ux * uy, c2a * uy * uz, c2b * (2.0f * zz - xx - yy),
                  c2a * ux * uz, c2c * (xx - yy)};

  const float c3a = 0.59004358992664352f;
  const float c3b = 2.89061144264055405f;
  const float c3c = 0.45704579946446574f;
  const float c3d = 0.37317633259011546f;
  const float c3e = 1.44530572132027702f;
  float sh3[7] = {c3a * uy * (3.0f * xx - yy),
                  c3b * ux * uy * uz,
                  c3c * uy * (4.0f * zz - xx - yy),
                  c3d * uz * (2.0f * zz - 3.0f * xx - 3.0f * yy),
                  c3c * ux * (4.0f * zz - xx - yy),
                  c3e * uz * (xx - yy),
                  c3a * ux * (xx - 3.0f * yy)};

  const size_t E_ = (size_t)E;
  float* lw = reinterpret_cast<float*>(lbuf[wave]);
  float vals[35];

  // ---- block 0: [E,1,8] @ 0 ----
  const float y0c = 0.28209479177387814f;
#pragma unroll
  for (int n = 0; n < 8; ++n) vals[n] = y0c * rb[n];
  if (fullwave) {
    stage_flush<8>(lw, vals, lane, reinterpret_cast<fx4*>(out + (size_t)e0 * 8));
  } else if (valid) {
    float* o = out + (size_t)e * 8;
#pragma unroll
    for (int i = 0; i < 8; ++i) o[i] = vals[i];
  }

  // ---- block 1: [E,3,7] @ 8E ----
#pragma unroll
  for (int m = 0; m < 3; ++m)
#pragma unroll
    for (int n = 0; n < 7; ++n) vals[m * 7 + n] = sh1[m] * rb[n];
  if (fullwave) {
    stage_flush<21>(lw, vals, lane,
                    reinterpret_cast<fx4*>(out + 8 * E_ + (size_t)e0 * 21));
  } else if (valid) {
    float* o = out + 8 * E_ + (size_t)e * 21;
#pragma unroll
    for (int i = 0; i < 21; ++i) o[i] = vals[i];
  }

  // ---- block 2: [E,5,6] @ 29E ----
#pragma unroll
  for (int m = 0; m < 5; ++m)
#pragma unroll
    for (int n = 0; n < 6; ++n) vals[m * 6 + n] = sh2[m] * rb[n];
  if (fullwave) {
    stage_flush<30>(lw, vals, lane,
                    reinterpret_cast<fx4*>(out + 29 * E_ + (size_t)e0 * 30));
  } else if (valid) {
    float* o = out + 29 * E_ + (size_t)e * 30;
#pragma unroll
    for (int i = 0; i < 30; ++i) o[i] = vals[i];
  }

  // ---- block 3: [E,7,5] @ 59E ----
#pragma unroll
  for (int m = 0; m < 7; ++m)
#pragma unroll
    for (int n = 0; n < 5; ++n) vals[m * 5 + n] = sh3[m] * rb[n];
  if (fullwave) {
    stage_flush<35>(lw, vals, lane,
                    reinterpret_cast<fx4*>(out + 59 * E_ + (size_t)e0 * 35));
  } else if (valid) {
    float* o = out + 59 * E_ + (size_t)e * 35;
#pragma unroll
    for (int i = 0; i < 35; ++i) o[i] = vals[i];
  }
}

extern "C" void kernel_launch(void* const* d_in, const int* in_sizes, int n_in,
                              void* d_out, int out_size, void* d_ws, size_t ws_size,
                              hipStream_t stream) {
  const float* v = (const float*)d_in[0];
  float* out = (float*)d_out;
  int E = in_sizes[0] / 3;
  int waves = (E + 63) / 64;
  int grid = (waves + 3) / 4;  // 4 waves (256 threads) per block
  vexp_kernel<<<grid, 256, 0, stream>>>(v, out, E);
}